// Round 1
// baseline (963.079 us; speedup 1.0000x reference)
//
#include <hip/hip_runtime.h>
#include <hip/hip_bf16.h>

typedef __bf16 bf16x8 __attribute__((ext_vector_type(8)));
typedef float  f32x4  __attribute__((ext_vector_type(4)));
typedef unsigned short u16;

#define T_N 512
#define H_N 256
#define B_N 4
#define V_N 8192
#define E_N 64

__device__ __forceinline__ float tanh_fast(float x) {
    // tanh(x) = 1 - 2/(1+e^{2x}); exact identity, ~3e-7 abs err in fp32
    float e = __expf(2.0f * x);
    return 1.0f - __fdividef(2.0f, e + 1.0f);
}

__device__ __forceinline__ u16 f2bf(float f) {
    __hip_bfloat16 h = __float2bfloat16(f);   // RTNE
    return __builtin_bit_cast(u16, h);
}

__device__ __forceinline__ bf16x8 as_bf16x8(uint4 u) {
    return __builtin_bit_cast(bf16x8, u);
}

__device__ __forceinline__ uint4 pack_bf8(f32x4 lo, f32x4 hi) {
    union { u16 s[8]; uint4 u; } r;
    #pragma unroll
    for (int e = 0; e < 4; ++e) { r.s[e] = f2bf(lo[e]); r.s[e+4] = f2bf(hi[e]); }
    return r.u;
}

__device__ __forceinline__ f32x4 mfma16(bf16x8 a, bf16x8 b, f32x4 c) {
    return __builtin_amdgcn_mfma_f32_16x16x32_bf16(a, b, c, 0, 0, 0);
}

// ---------------------------------------------------------------------------
// fp32 -> bf16 convert (n4 = n/4)
__global__ void cvt_bf16_kernel(const float* __restrict__ src, u16* __restrict__ dst, int n4) {
    int i = blockIdx.x * 256 + threadIdx.x;
    if (i < n4) {
        f32x4 v = ((const f32x4*)src)[i];
        union { u16 s[4]; unsigned long long u; } r;
        #pragma unroll
        for (int e = 0; e < 4; ++e) r.s[e] = f2bf(v[e]);
        ((unsigned long long*)dst)[i] = r.u;
    }
}

// ---------------------------------------------------------------------------
// embedding gather + xW0 = e @ W_ih0^T + b_ih0 + b_hh0, stored [t][j][b] f32
__global__ __launch_bounds__(256)
void embed_xw0_kernel(const int* __restrict__ x, const float* __restrict__ emb,
                      const float* __restrict__ Wih, const float* __restrict__ bih,
                      const float* __restrict__ bhh, float* __restrict__ xw0) {
    const int t = blockIdx.x, tid = threadIdx.x;
    __shared__ float sE[4][64];
    {
        const int b = tid >> 6, k = tid & 63;
        sE[b][k] = emb[(size_t)x[b * T_N + t] * E_N + k];
    }
    __syncthreads();
    const int j = tid;
    const float* wr = Wih + j * E_N;
    float a0 = 0, a1 = 0, a2 = 0, a3 = 0;
    #pragma unroll 8
    for (int k = 0; k < E_N; ++k) {
        float wv = wr[k];
        a0 += sE[0][k] * wv; a1 += sE[1][k] * wv;
        a2 += sE[2][k] * wv; a3 += sE[3][k] * wv;
    }
    const float bs = bih[j] + bhh[j];
    f32x4 o = { a0 + bs, a1 + bs, a2 + bs, a3 + bs };
    *(f32x4*)(xw0 + ((size_t)t * H_N + j) * 4) = o;
}

// ---------------------------------------------------------------------------
// Sequential tanh-RNN recurrence on ONE workgroup (4 waves, 1 CU).
// W_hh held entirely in VGPRs as MFMA B-fragments. h state ping-pongs in LDS
// (XOR-swizzled rows -> conflict-free ds_read_b128 A-fragments).
// xw: [T][H][B] f32 (precomputed input+bias term). Outputs y as bf16 [B][T][H]
// (+ optional f32 copy), and final h_T fp32.
template<int STORE_F32>
__global__ __launch_bounds__(256, 1)
void rnn_rec_kernel(const float* __restrict__ Whh, const float* __restrict__ xw,
                    u16* __restrict__ ybf, float* __restrict__ yf32,
                    float* __restrict__ hT) {
    __shared__ __align__(16) u16   hbuf[2][16][H_N];  // 16KB, rows 4..15 stay zero
    __shared__ __align__(16) float tmp[4][64][4];     // per-wave [j_local][b] bounce

    const int tid = threadIdx.x;
    const int w = tid >> 6, l = tid & 63;
    const int m = l & 15, g = l >> 4;
    const int jmy = (w << 6) + l;                     // this lane's output feature j

    for (int idx = tid; idx < 2 * 16 * H_N; idx += 256) (&hbuf[0][0][0])[idx] = 0;

    // ---- stage W_hh into registers as B-fragments: B[k][j] = W[j][k] ----
    bf16x8 wfrag[4][8];
    #pragma unroll
    for (int nt = 0; nt < 4; ++nt) {
        const int j = (w << 6) + (nt << 4) + m;
        #pragma unroll
        for (int kk = 0; kk < 8; ++kk) {
            const float* p = Whh + (size_t)j * H_N + (kk << 5) + (g << 3);
            f32x4 lo = *(const f32x4*)p;
            f32x4 hi = *(const f32x4*)(p + 4);
            wfrag[nt][kk] = as_bf16x8(pack_bf8(lo, hi));
        }
    }

    const f32x4* xwv = (const f32x4*)xw;
    f32x4 xw_cur = xwv[jmy];                          // t = 0
    __syncthreads();

    int cur = 0;
    for (int t = 0; t < T_N; ++t) {
        const int tn = (t + 1 < T_N) ? (t + 1) : t;
        f32x4 xw_nxt = xwv[(size_t)tn * H_N + jmy];   // prefetch next step

        // A-fragments: A[b][k] from swizzled hbuf (b = lane&15; rows>=4 are zero)
        bf16x8 af[8];
        const char* hb = (const char*)&hbuf[cur][0][0];
        #pragma unroll
        for (int kk = 0; kk < 8; ++kk) {
            int byte = (m << 9) + (kk << 6) + (g << 4);
            byte ^= (m & 7) << 4;
            af[kk] = as_bf16x8(*(const uint4*)(hb + byte));
        }

        f32x4 c[4];
        #pragma unroll
        for (int nt = 0; nt < 4; ++nt) c[nt] = (f32x4){0.f, 0.f, 0.f, 0.f};
        #pragma unroll
        for (int kk = 0; kk < 8; ++kk)
            #pragma unroll
            for (int nt = 0; nt < 4; ++nt)
                c[nt] = mfma16(af[kk], wfrag[nt][kk], c[nt]);

        // redistribute C (lives on lanes 0-15, reg r = batch) to all 64 lanes
        if (g == 0) {
            #pragma unroll
            for (int nt = 0; nt < 4; ++nt)
                *(f32x4*)&tmp[w][(nt << 4) + m][0] = c[nt];
        }
        f32x4 hv = *(const f32x4*)&tmp[w][l][0];      // lane -> j = jmy, 4 batches
        hv += xw_cur;

        char* hbn = (char*)&hbuf[cur ^ 1][0][0];
        #pragma unroll
        for (int b = 0; b < 4; ++b) {
            float hn = tanh_fast(hv[b]);
            u16 bits = f2bf(hn);
            int byte = (b << 9) + (jmy << 1);
            byte ^= (b & 7) << 4;                      // same swizzle as reads
            *(u16*)(hbn + byte) = bits;
            ybf[((size_t)b * T_N + t) * H_N + jmy] = bits;
            if (STORE_F32) yf32[((size_t)b * T_N + t) * H_N + jmy] = hn;
            if (t == T_N - 1) hT[b * H_N + jmy] = hn;
        }
        xw_cur = xw_nxt;
        cur ^= 1;
        __syncthreads();
    }
}

// ---------------------------------------------------------------------------
// bf16 MFMA GEMM: out[row][col] = sum_k A[row][k]*B[col][k] (+bias[col](+bias2))
// MODE 0: out f32 [row][N]; MODE 1: out f32 [t][N][4] (row=b*512+t, N=256);
// MODE 2: out f32 [b][N][512] transposed (kT), N=256.
template<int MODE>
__global__ __launch_bounds__(256, 2)
void gemm_bf16(const u16* __restrict__ A, const u16* __restrict__ Bw,
               float* __restrict__ out, const float* __restrict__ bias,
               const float* __restrict__ bias2, int M, int N, int K) {
    __shared__ __align__(16) u16 As[64][40];  // rows padded to 80B -> ~2-way only
    __shared__ __align__(16) u16 Bs[64][40];
    const int tid = threadIdx.x;
    const int nb = N >> 6;
    const int bm = blockIdx.x / nb, bn = blockIdx.x % nb;
    const int l = tid & 63, w = tid >> 6;
    const int wm = w & 1, wn = w >> 1;
    const int m = l & 15, g = l >> 4;
    const int srow = tid >> 2, sseg = tid & 3;

    f32x4 c[2][2];
    #pragma unroll
    for (int i = 0; i < 2; ++i)
        #pragma unroll
        for (int j = 0; j < 2; ++j) c[i][j] = (f32x4){0.f, 0.f, 0.f, 0.f};

    const u16* ap = A  + (size_t)(bm * 64 + srow) * K + sseg * 8;
    const u16* bp = Bw + (size_t)(bn * 64 + srow) * K + sseg * 8;

    for (int k0 = 0; k0 < K; k0 += 32) {
        uint4 av = *(const uint4*)(ap + k0);
        uint4 bv = *(const uint4*)(bp + k0);
        __syncthreads();
        *(uint4*)&As[srow][sseg << 3] = av;
        *(uint4*)&Bs[srow][sseg << 3] = bv;
        __syncthreads();
        bf16x8 af[2], bfr[2];
        #pragma unroll
        for (int i = 0; i < 2; ++i) {
            af[i]  = as_bf16x8(*(const uint4*)&As[(wm << 5) + (i << 4) + m][g << 3]);
            bfr[i] = as_bf16x8(*(const uint4*)&Bs[(wn << 5) + (i << 4) + m][g << 3]);
        }
        #pragma unroll
        for (int i = 0; i < 2; ++i)
            #pragma unroll
            for (int j = 0; j < 2; ++j)
                c[i][j] = mfma16(af[i], bfr[j], c[i][j]);
    }

    #pragma unroll
    for (int i = 0; i < 2; ++i)
        #pragma unroll
        for (int j = 0; j < 2; ++j) {
            const int col = (bn << 6) + (wn << 5) + (j << 4) + m;
            float bs = 0.f;
            if (bias)  bs += bias[col];
            if (bias2) bs += bias2[col];
            #pragma unroll
            for (int r = 0; r < 4; ++r) {
                const int row = (bm << 6) + (wm << 5) + (i << 4) + (g << 2) + r;
                const float val = c[i][j][r] + bs;
                if (MODE == 0) {
                    out[(size_t)row * N + col] = val;
                } else if (MODE == 1) {
                    const int b = row >> 9, t = row & 511;
                    out[((size_t)t * N + col) * 4 + b] = val;
                } else {
                    const int b = row >> 9, t = row & 511;
                    out[(size_t)b * N * T_N + (size_t)col * T_N + t] = val;
                }
            }
        }
}

// ---------------------------------------------------------------------------
// Bahdanau attention, one block per (b, i): scores_j = sum_h v[h]*tanh(q+k),
// causal softmax, ctx = alpha @ y1.
__global__ __launch_bounds__(256)
void attn_kernel(const float* __restrict__ q, const float* __restrict__ kT,
                 const float* __restrict__ y1f, const float* __restrict__ vvec,
                 float* __restrict__ ctx) {
    const int blk = blockIdx.x;
    const int b = blk >> 9, i = blk & 511;
    const int tid = threadIdx.x;
    __shared__ float sQ[H_N], sV[H_N], sS[T_N];
    __shared__ float red[4];
    sQ[tid] = q[((size_t)b * T_N + i) * H_N + tid];
    sV[tid] = vvec[tid];
    __syncthreads();

    float s0 = -1e30f, s1 = -1e30f;
    if (tid <= i) {
        const float* kp = kT + (size_t)b * H_N * T_N + tid;
        float acc = 0.f;
        for (int h = 0; h < H_N; ++h) acc += sV[h] * tanh_fast(sQ[h] + kp[(size_t)h * T_N]);
        s0 = acc;
    }
    if (tid + 256 <= i) {
        const float* kp = kT + (size_t)b * H_N * T_N + tid + 256;
        float acc = 0.f;
        for (int h = 0; h < H_N; ++h) acc += sV[h] * tanh_fast(sQ[h] + kp[(size_t)h * T_N]);
        s1 = acc;
    }
    float mv = fmaxf(s0, s1);
    #pragma unroll
    for (int o = 32; o; o >>= 1) mv = fmaxf(mv, __shfl_xor(mv, o, 64));
    if ((tid & 63) == 0) red[tid >> 6] = mv;
    __syncthreads();
    mv = fmaxf(fmaxf(red[0], red[1]), fmaxf(red[2], red[3]));
    __syncthreads();
    float e0 = (tid <= i)       ? __expf(s0 - mv) : 0.f;
    float e1 = (tid + 256 <= i) ? __expf(s1 - mv) : 0.f;
    float sm = e0 + e1;
    #pragma unroll
    for (int o = 32; o; o >>= 1) sm += __shfl_xor(sm, o, 64);
    if ((tid & 63) == 0) red[tid >> 6] = sm;
    __syncthreads();
    sm = red[0] + red[1] + red[2] + red[3];
    const float rs = 1.0f / sm;
    sS[tid] = e0 * rs;
    sS[tid + 256] = e1 * rs;
    __syncthreads();
    float acc = 0.f;
    const float* yp = y1f + (size_t)b * T_N * H_N + tid;
    for (int j2 = 0; j2 <= i; ++j2) acc += sS[j2] * yp[(size_t)j2 * H_N];
    ctx[((size_t)b * T_N + i) * H_N + tid] = acc;
}

// ---------------------------------------------------------------------------
// LayerNorm over cat([y1, ctx]) (512), output bf16 [row][512]
__global__ __launch_bounds__(256)
void ln_kernel(const float* __restrict__ y1f, const float* __restrict__ ctx,
               const float* __restrict__ gamma, const float* __restrict__ beta,
               u16* __restrict__ outbf) {
    const int row = blockIdx.x, tid = threadIdx.x;
    __shared__ float red[4];
    const float x1 = y1f[(size_t)row * H_N + tid];
    const float x2 = ctx[(size_t)row * H_N + tid];
    float s = x1 + x2;
    #pragma unroll
    for (int o = 32; o; o >>= 1) s += __shfl_xor(s, o, 64);
    if ((tid & 63) == 0) red[tid >> 6] = s;
    __syncthreads();
    const float mu = (red[0] + red[1] + red[2] + red[3]) * (1.f / 512.f);
    __syncthreads();
    const float d1 = x1 - mu, d2 = x2 - mu;
    float qv = d1 * d1 + d2 * d2;
    #pragma unroll
    for (int o = 32; o; o >>= 1) qv += __shfl_xor(qv, o, 64);
    if ((tid & 63) == 0) red[tid >> 6] = qv;
    __syncthreads();
    const float var = (red[0] + red[1] + red[2] + red[3]) * (1.f / 512.f);
    const float inv = rsqrtf(var + 1e-5f);
    outbf[(size_t)row * 512 + tid]       = f2bf(d1 * inv * gamma[tid] + beta[tid]);
    outbf[(size_t)row * 512 + tid + 256] = f2bf(d2 * inv * gamma[tid + 256] + beta[tid + 256]);
}

// ---------------------------------------------------------------------------
extern "C" void kernel_launch(void* const* d_in, const int* in_sizes, int n_in,
                              void* d_out, int out_size, void* d_ws, size_t ws_size,
                              hipStream_t stream) {
    const int*   x     = (const int*)  d_in[0];
    const float* emb   = (const float*)d_in[1];
    const float* Wih0  = (const float*)d_in[2];
    const float* Whh0  = (const float*)d_in[3];
    const float* bih0  = (const float*)d_in[4];
    const float* bhh0  = (const float*)d_in[5];
    const float* Wih1  = (const float*)d_in[6];
    const float* Whh1  = (const float*)d_in[7];
    const float* bih1  = (const float*)d_in[8];
    const float* bhh1  = (const float*)d_in[9];
    const float* Wq    = (const float*)d_in[10];
    const float* Wk    = (const float*)d_in[11];
    const float* vvec  = (const float*)d_in[12];
    const float* gamma = (const float*)d_in[13];
    const float* beta  = (const float*)d_in[14];
    const float* Wfc   = (const float*)d_in[15];
    const float* bfc   = (const float*)d_in[16];

    float* outp = (float*)d_out;
    char* ws = (char*)d_ws;
    float* xw0   = (float*)(ws + 0);         // 2MB  [T][H][B]
    float* xw1   = (float*)(ws + 2097152);   // 2MB  [T][H][B]
    u16*   y0bf  = (u16*)  (ws + 4194304);   // 1MB  [B][T][H]
    u16*   y1bf  = (u16*)  (ws + 5242880);   // 1MB
    float* y1f   = (float*)(ws + 6291456);   // 2MB  [B][T][H]
    float* qf    = (float*)(ws + 8388608);   // 2MB  [B][T][H]
    float* kT    = (float*)(ws + 10485760);  // 2MB  [B][H][T]
    float* ctx   = (float*)(ws + 12582912);  // 2MB  [B][T][H]
    u16*   nrm   = (u16*)  (ws + 14680064);  // 2MB  [B*T][512]
    u16*   Wih1b = (u16*)  (ws + 16777216);
    u16*   Wqb   = (u16*)  (ws + 16908288);
    u16*   Wkb   = (u16*)  (ws + 17039360);
    u16*   Wfcb  = (u16*)  (ws + 17170432);  // 8MB

    float* hout = outp + (size_t)B_N * T_N * V_N;   // h output after logits

    cvt_bf16_kernel<<<64,   256, 0, stream>>>(Wih1, Wih1b, 65536 / 4);
    cvt_bf16_kernel<<<64,   256, 0, stream>>>(Wq,   Wqb,   65536 / 4);
    cvt_bf16_kernel<<<64,   256, 0, stream>>>(Wk,   Wkb,   65536 / 4);
    cvt_bf16_kernel<<<4096, 256, 0, stream>>>(Wfc,  Wfcb,  4194304 / 4);

    embed_xw0_kernel<<<512, 256, 0, stream>>>(x, emb, Wih0, bih0, bhh0, xw0);
    rnn_rec_kernel<0><<<1, 256, 0, stream>>>(Whh0, xw0, y0bf, nullptr, hout);
    gemm_bf16<1><<<32 * 4, 256, 0, stream>>>(y0bf, Wih1b, xw1, bih1, bhh1, 2048, 256, 256);
    rnn_rec_kernel<1><<<1, 256, 0, stream>>>(Whh1, xw1, y1bf, y1f, hout + 1024);
    gemm_bf16<0><<<32 * 4, 256, 0, stream>>>(y1bf, Wqb, qf, nullptr, nullptr, 2048, 256, 256);
    gemm_bf16<2><<<32 * 4, 256, 0, stream>>>(y1bf, Wkb, kT, nullptr, nullptr, 2048, 256, 256);
    attn_kernel<<<2048, 256, 0, stream>>>(qf, kT, y1f, vvec, ctx);
    ln_kernel<<<2048, 256, 0, stream>>>(y1f, ctx, gamma, beta, nrm);
    gemm_bf16<0><<<32 * 128, 256, 0, stream>>>(nrm, Wfcb, outp, bfc, nullptr, 2048, 8192, 512);
}